// Round 2
// baseline (3403.999 us; speedup 1.0000x reference)
//
#include <hip/hip_runtime.h>

typedef unsigned int u32;
typedef _Float16 half_t;
typedef _Float16 half2_t __attribute__((ext_vector_type(2)));

#define B_ 64
#define T_ 2048
#define I_ 128
#define H_ 512
#define O_ 128

static __device__ __forceinline__ float dot2w(u32 w, u32 h, float acc) {
  return __builtin_amdgcn_fdot2(__builtin_bit_cast(half2_t, w),
                                __builtin_bit_cast(half2_t, h), acc, false);
}

// ---------------- K1: pack masked weights to fp16 layouts ----------------
// Whh_pk layout: word q (=j*32+m) of lane l stored at [ (q/4)*2048 + l*4 + (q&3) ]
//   lane l owns rows r_j = (l>>3)*8 + j (j=0..7), k-range [ (l&7)*64, +64 )
__global__ void k_prep(const float* __restrict__ Whh, const float* __restrict__ Mhh,
                       const float* __restrict__ Wih, const float* __restrict__ Mih,
                       const float* __restrict__ Wfc,
                       u32* __restrict__ Whh_pk, u32* __restrict__ Wih_pk,
                       u32* __restrict__ Wfc_pk) {
  int idx = blockIdx.x * 256 + threadIdx.x;
  if (idx < 512 * 256) {
    int w4 = idx >> 11;
    int rem = idx & 2047;
    int l = rem >> 2;
    int c = rem & 3;
    int q = w4 * 4 + c;
    int j = q >> 5;
    int m = q & 31;
    int row = (l >> 3) * 8 + j;
    int k0 = (l & 7) * 64 + m * 2;
    float a = Whh[row * 512 + k0]     * Mhh[row * 512 + k0];
    float b = Whh[row * 512 + k0 + 1] * Mhh[row * 512 + k0 + 1];
    half2_t hv = { (half_t)a, (half_t)b };
    Whh_pk[idx] = __builtin_bit_cast(u32, hv);
  } else if (idx < 512 * 256 + 512 * 64) {
    int i2 = idx - 512 * 256;
    int h = i2 >> 6, w = i2 & 63;
    int k0 = w * 2;
    float a = Wih[h * 128 + k0]     * Mih[h * 128 + k0];
    float b = Wih[h * 128 + k0 + 1] * Mih[h * 128 + k0 + 1];
    half2_t hv = { (half_t)a, (half_t)b };
    Wih_pk[h * 64 + w] = __builtin_bit_cast(u32, hv);
  } else if (idx < 512 * 256 + 512 * 64 + 128 * 256) {
    int i3 = idx - (512 * 256 + 512 * 64);
    int o = i3 >> 8, w = i3 & 255;
    float a = Wfc[o * 512 + 2 * w];
    float b = Wfc[o * 512 + 2 * w + 1];
    half2_t hv = { (half_t)a, (half_t)b };
    Wfc_pk[o * 256 + w] = __builtin_bit_cast(u32, hv);
  }
}

// ---------------- K2: xproj[b][t][h] = x . Wih_m^T + b_ih + b_hh (fp16 out) ----
__launch_bounds__(512, 2)
__global__ void k_xproj(const float* __restrict__ x, const u32* __restrict__ Wih_pk,
                        const float* __restrict__ b_ih, const float* __restrict__ b_hh,
                        half_t* __restrict__ xp) {
  const int l = threadIdx.x;           // l = h
  const int r0 = blockIdx.x * 256;     // 256 (b,t) rows per block
  __shared__ u32 xb[2][64];
  u32 W[64];
#pragma unroll
  for (int i = 0; i < 16; ++i)
    *(uint4*)&W[i * 4] = *(const uint4*)(Wih_pk + l * 64 + i * 4);
  const float bs = b_ih[l] + b_hh[l];

  float2 g = { 0.f, 0.f };
  if (l < 64) {
    g = *(const float2*)(x + (size_t)r0 * 128 + 2 * l);
    half2_t hv = { (half_t)g.x, (half_t)g.y };
    xb[0][l] = __builtin_bit_cast(u32, hv);
    g = *(const float2*)(x + (size_t)(r0 + 1) * 128 + 2 * l);
  }
  __syncthreads();
  for (int i = 0; i < 256; ++i) {
    if (l < 64 && i + 1 < 256) {
      half2_t hv = { (half_t)g.x, (half_t)g.y };
      xb[(i + 1) & 1][l] = __builtin_bit_cast(u32, hv);
      int nf = (i + 2 < 256) ? i + 2 : i + 1;
      g = *(const float2*)(x + (size_t)(r0 + nf) * 128 + 2 * l);
    }
    float a0 = 0.f, a1 = 0.f;
#pragma unroll
    for (int m = 0; m < 16; ++m) {
      uint4 hv = *(const uint4*)&xb[i & 1][m * 4];
      a0 = dot2w(W[m * 4 + 0], hv.x, a0);
      a1 = dot2w(W[m * 4 + 1], hv.y, a1);
      a0 = dot2w(W[m * 4 + 2], hv.z, a0);
      a1 = dot2w(W[m * 4 + 3], hv.w, a1);
    }
    xp[(size_t)(r0 + i) * 512 + l] = (half_t)(a0 + a1 + bs);
    __syncthreads();
  }
}

// ---------------- K3: recurrence, one block per batch element ----------------
// NOTE: hs aliases xp (same buffer). Safe: xp[b][t] is last READ at iteration
// t-2 (2-deep prefetch); h[b][t] is WRITTEN at iteration t, two __syncthreads
// later. Blocks touch disjoint b slices.
__launch_bounds__(512, 2)
__global__ void k_rec(const u32* __restrict__ Whh_pk, half_t* __restrict__ xp,
                      const float* __restrict__ h0) {
  const int b = blockIdx.x;
  const int l = threadIdx.x;
  const int g = l & 7;                  // k-group: k in [g*64, g*64+64)
  const int row = l;                    // (l>>3)*8 + (l&7) == l

  __shared__ u32 hbuf[2][288];          // h fp16 packed; 32-word chunks padded +4
  __shared__ u32 wlds[512 * 52];        // LDS-resident weight words (stride 52 u32)

  // load resident weights: 208 u32 -> VGPRs, 48 u32 -> LDS
  u32 W[208];
#pragma unroll
  for (int w4 = 0; w4 < 64; ++w4) {
    uint4 v = *(const uint4*)(Whh_pk + (size_t)w4 * 2048 + l * 4);
    const int j = w4 >> 3, p = w4 & 7;
    if (j < 4) {
      if (p < 7) {
        W[j * 28 + p * 4 + 0] = v.x; W[j * 28 + p * 4 + 1] = v.y;
        W[j * 28 + p * 4 + 2] = v.z; W[j * 28 + p * 4 + 3] = v.w;
      } else {
        *(uint4*)&wlds[l * 52 + j * 4] = v;
      }
    } else {
      if (p < 6) {
        int base = 112 + (j - 4) * 24 + p * 4;
        W[base + 0] = v.x; W[base + 1] = v.y; W[base + 2] = v.z; W[base + 3] = v.w;
      } else {
        *(uint4*)&wlds[l * 52 + 16 + (j - 4) * 8 + (p - 6) * 4] = v;
      }
    }
  }
  // initial h from h0 (padded-chunk layout: word w goes to w + (w/32)*4)
  if (l < 256) {
    float2 hv = *(const float2*)(h0 + (size_t)b * 512 + 2 * l);
    half2_t hh = { (half_t)hv.x, (half_t)hv.y };
    hbuf[0][l + (l >> 5) * 4] = __builtin_bit_cast(u32, hh);
  }
  __syncthreads();

  half_t* xpb = xp + (size_t)b * T_ * 512 + row;
  half_t xp0 = xpb[0];
  half_t xp1 = xpb[512];

  const int b0 = l & 1, b1 = (l >> 1) & 1, b2 = (l >> 2) & 1;
  const int hwIdx = (row >> 1) + (row >> 6) * 4;   // padded word index of row's halfword
  int cur = 0;

  for (int t = 0; t < T_; ++t) {
    int tpf = (t + 2 < T_) ? t + 2 : T_ - 1;
    half_t xpn = xpb[(size_t)tpf * 512];           // prefetch 2 steps ahead

    float acc[8];
#pragma unroll
    for (int j = 0; j < 8; ++j) acc[j] = 0.f;

#pragma unroll
    for (int m4 = 0; m4 < 8; ++m4) {
      uint4 hh = *(const uint4*)&hbuf[cur][g * 36 + m4 * 4];
#pragma unroll
      for (int j = 0; j < 8; ++j) {
        u32 w0, w1, w2, w3;
        if (j < 4) {
          if (m4 < 7) {
            w0 = W[j * 28 + m4 * 4 + 0]; w1 = W[j * 28 + m4 * 4 + 1];
            w2 = W[j * 28 + m4 * 4 + 2]; w3 = W[j * 28 + m4 * 4 + 3];
          } else {
            uint4 wv = *(const uint4*)&wlds[l * 52 + j * 4];
            w0 = wv.x; w1 = wv.y; w2 = wv.z; w3 = wv.w;
          }
        } else {
          if (m4 < 6) {
            int base = 112 + (j - 4) * 24 + m4 * 4;
            w0 = W[base + 0]; w1 = W[base + 1]; w2 = W[base + 2]; w3 = W[base + 3];
          } else {
            uint4 wv = *(const uint4*)&wlds[l * 52 + 16 + (j - 4) * 8 + (m4 - 6) * 4];
            w0 = wv.x; w1 = wv.y; w2 = wv.z; w3 = wv.w;
          }
        }
        acc[j] = dot2w(w0, hh.x, acc[j]);
        acc[j] = dot2w(w1, hh.y, acc[j]);
        acc[j] = dot2w(w2, hh.z, acc[j]);
        acc[j] = dot2w(w3, hh.w, acc[j]);
      }
    }

    // keep-half butterfly over the 8-lane k-group dim; lane g ends with row r_g total
    float s4[4];
#pragma unroll
    for (int m = 0; m < 4; ++m) {
      float keep = b0 ? acc[2 * m + 1] : acc[2 * m];
      float send = b0 ? acc[2 * m]     : acc[2 * m + 1];
      s4[m] = keep + __shfl_xor(send, 1, 64);
    }
    float s2[2];
#pragma unroll
    for (int m = 0; m < 2; ++m) {
      float keep = b1 ? s4[2 * m + 1] : s4[2 * m];
      float send = b1 ? s4[2 * m]     : s4[2 * m + 1];
      s2[m] = keep + __shfl_xor(send, 2, 64);
    }
    float keepf = b2 ? s2[1] : s2[0];
    float sendf = b2 ? s2[0] : s2[1];
    float tot = keepf + __shfl_xor(sendf, 4, 64);

    float sarg = tot + (float)xp0;
    float ax = fabsf(sarg);
    float e = __expf(-2.f * ax);
    float r = (1.f - e) * __builtin_amdgcn_rcpf(1.f + e);
    float hval = copysignf(r, sarg);

    half_t hv = (half_t)hval;
    ((half_t*)hbuf[cur ^ 1])[hwIdx * 2 + (row & 1)] = hv;
    xpb[(size_t)t * 512] = hv;            // overwrite consumed xproj slot with h

    xp0 = xp1; xp1 = xpn;
    __syncthreads();
    cur ^= 1;
  }
}

// ---------------- K4: readout out[b][t][o] = hs . Wfc^T + b_fc ----------------
__launch_bounds__(256, 2)
__global__ void k_fc(const half_t* __restrict__ hs, const u32* __restrict__ Wfc_pk,
                     const float* __restrict__ b_fc, float* __restrict__ out) {
  const int l = threadIdx.x;
  const int w = l >> 6;                       // wave 0..3
  const int o = (l & 31) + w * 32;
  const int kh = (l >> 5) & 1;                // k half
  const int r0 = blockIdx.x * 256;
  __shared__ u32 sb[2][256];
  u32 W[128];
#pragma unroll
  for (int i = 0; i < 32; ++i)
    *(uint4*)&W[i * 4] = *(const uint4*)(Wfc_pk + o * 256 + kh * 128 + i * 4);
  const float bf = b_fc[o];
  const u32* hsw = (const u32*)hs;

  u32 gA = hsw[(size_t)r0 * 256 + l];
  sb[0][l] = gA;
  gA = hsw[(size_t)(r0 + 1) * 256 + l];
  __syncthreads();
  for (int i = 0; i < 256; ++i) {
    if (i + 1 < 256) {
      sb[(i + 1) & 1][l] = gA;
      int nf = (i + 2 < 256) ? i + 2 : i + 1;
      gA = hsw[(size_t)(r0 + nf) * 256 + l];
    }
    float a0 = 0.f, a1 = 0.f;
#pragma unroll
    for (int m = 0; m < 32; ++m) {
      uint4 hv = *(const uint4*)&sb[i & 1][kh * 128 + m * 4];
      a0 = dot2w(W[m * 4 + 0], hv.x, a0);
      a1 = dot2w(W[m * 4 + 1], hv.y, a1);
      a0 = dot2w(W[m * 4 + 2], hv.z, a0);
      a1 = dot2w(W[m * 4 + 3], hv.w, a1);
    }
    float a = a0 + a1;
    a += __shfl_xor(a, 32, 64);
    if (kh == 0) out[(size_t)(r0 + i) * 128 + o] = a + bf;
    __syncthreads();
  }
}

extern "C" void kernel_launch(void* const* d_in, const int* in_sizes, int n_in,
                              void* d_out, int out_size, void* d_ws, size_t ws_size,
                              hipStream_t stream) {
  const float* x   = (const float*)d_in[0];
  const float* h0  = (const float*)d_in[1];
  const float* Wih = (const float*)d_in[2];
  const float* bih = (const float*)d_in[3];
  const float* Whh = (const float*)d_in[4];
  const float* bhh = (const float*)d_in[5];
  const float* Mih = (const float*)d_in[6];
  const float* Mhh = (const float*)d_in[7];
  const float* Wfc = (const float*)d_in[8];
  const float* bfc = (const float*)d_in[9];
  float* out = (float*)d_out;

  char* ws = (char*)d_ws;
  // layout (total ~128.8 MB):
  //   xproj/hs shared fp16 buffer (128 MB) | Whh_pk (512KB) | Wih_pk (128KB) | Wfc_pk (128KB)
  half_t* xproj = (half_t*)(ws);                         // aliased: becomes hs after k_rec
  u32* Whh_pk = (u32*)(ws + 134217728);
  u32* Wih_pk = (u32*)(ws + 134217728 + 524288);
  u32* Wfc_pk = (u32*)(ws + 134217728 + 524288 + 131072);

  hipLaunchKernelGGL(k_prep, dim3(768), dim3(256), 0, stream,
                     Whh, Mhh, Wih, Mih, Wfc, Whh_pk, Wih_pk, Wfc_pk);
  hipLaunchKernelGGL(k_xproj, dim3(512), dim3(512), 0, stream,
                     x, Wih_pk, bih, bhh, xproj);
  hipLaunchKernelGGL(k_rec, dim3(64), dim3(512), 0, stream,
                     Whh_pk, xproj, h0);
  hipLaunchKernelGGL(k_fc, dim3(512), dim3(256), 0, stream,
                     xproj, Wfc_pk, bfc, out);
}